// Round 4
// baseline (4262.851 us; speedup 1.0000x reference)
//
#include <hip/hip_runtime.h>
#include <math.h>

#define NN 128
#define SM 129   // padded LDS stride for 128-wide f32 tiles

// ---------------------------------------------------------------------------
// K1: build symmetric-normalized Laplacian per graph
// ---------------------------------------------------------------------------
__global__ __launch_bounds__(256) void k1_laplacian(
    const int* __restrict__ src, const int* __restrict__ dst,
    int E, float* __restrict__ Lout) {
  extern __shared__ float sm1[];            // A[128*129] + dinv[128]
  float* A    = sm1;
  float* dinv = sm1 + NN * SM;
  const int g   = blockIdx.x;
  const int tid = threadIdx.x;

  for (int e = tid; e < NN * NN; e += 256) {
    int i = e >> 7, j = e & 127;
    A[i * SM + j] = 0.f;
  }
  __syncthreads();
  const int* s = src + (size_t)g * E;
  const int* d = dst + (size_t)g * E;
  for (int e = tid; e < E; e += 256) {
    int a = s[e], b = d[e];
    A[a * SM + b] = 1.f;     // benign races: all write 1.0
    A[b * SM + a] = 1.f;
  }
  __syncthreads();
  if (tid < NN) {
    float acc = 0.f;
    for (int j = 0; j < NN; ++j) acc += A[tid * SM + j];
    dinv[tid] = (acc > 0.f) ? (float)(1.0 / sqrt((double)acc)) : 0.f;
  }
  __syncthreads();
  float* Lg = Lout + (size_t)g * NN * NN;
  for (int e = tid; e < NN * NN; e += 256) {
    int i = e >> 7, j = e & 127;
    Lg[e] = ((i == j) ? 1.f : 0.f) - dinv[i] * dinv[j] * A[i * SM + j];
  }
}

// ---------------------------------------------------------------------------
// K2: per (graph, filter): K = (L-bI)^4 + aI  ->  invert (fp64 GJ) ->
//     atomically accumulate  W += sqrt(2)*a*Cn[f] * K^{-1}
//
// Register-allocation ledger (measured):
//   launch_bounds(256,1) budget 512: 88 arch, kr->AGPR  -> shuffle tax, 1814us
//   launch_bounds(512,4) budget 128: 64 arch, kr->SCRATCH -> 21 GB spill, 3.9ms
// R4: launch_bounds(256,2) budget 256: kr[8][8] f64 (128) + ~50 working fits
// in ARCH VGPRs -> no AGPR moves, no spill; 2 blocks/CU (LDS 64.5KB caps at 2)
// with barrier overlap between the two blocks.
//
// Thread map (256 thr): tr=tid>>4 (0..15) owns rows 8tr+v; tc=tid&15 owns
// cols tc+16u (u=0..7). GJ: ONE barrier per pivot via double-buffered row/col
// broadcast buffers (publishers for pivot k use buffer k&1; reads of buffer
// (k-1)&1 completed before this barrier by program order).
// ---------------------------------------------------------------------------
__global__ __launch_bounds__(256, 2) void k2_filter(
    const float* __restrict__ L, const float* __restrict__ C,
    int NF, float* __restrict__ W) {
  extern __shared__ float sm2[];            // 128*129 f32 tile
  double* rowb = (double*)sm2;              // 2*128 doubles (aliases dead tile)
  double* colb = ((double*)sm2) + 256;      // 2*128 doubles
  const int bid = blockIdx.x;
  const int g = bid / NF;
  const int f = bid % NF;
  const int tid = threadIdx.x;
  const int tr = tid >> 4;                  // 0..15
  const int tc = tid & 15;                  // 0..15

  double csum = 0.0;
  for (int q = 0; q < NF; ++q) { double c = (double)C[q]; csum += c * c; }
  double cn = sqrt(csum); if (cn < 1e-12) cn = 1e-12;
  const double a4 = 0.05 * 0.05 * 0.05 * 0.05;               // (STEP/2)^4
  const double coef = 1.4142135623730951 * a4 * ((double)C[f] / cn);
  const float  bf = (float)((double)f * 0.1);

  // phase 1: M = L - b I  into LDS
  const float* Lg = L + (size_t)g * NN * NN;
  for (int e = tid; e < NN * NN; e += 256) {
    int i = e >> 7, j = e & 127;
    float v = Lg[e];
    if (i == j) v -= bf;
    sm2[i * SM + j] = v;
  }
  __syncthreads();

  // phase 2: P2 = M @ M   (fp32 regs, 8x8 per thread)
  float p2[8][8];
#pragma unroll
  for (int v = 0; v < 8; ++v)
#pragma unroll
    for (int u = 0; u < 8; ++u) p2[v][u] = 0.f;
  for (int k = 0; k < NN; ++k) {
    float av[8], bv[8];
#pragma unroll
    for (int v = 0; v < 8; ++v) av[v] = sm2[(8 * tr + v) * SM + k];
#pragma unroll
    for (int u = 0; u < 8; ++u) bv[u] = sm2[k * SM + tc + 16 * u];
#pragma unroll
    for (int v = 0; v < 8; ++v)
#pragma unroll
      for (int u = 0; u < 8; ++u) p2[v][u] = fmaf(av[v], bv[u], p2[v][u]);
  }
  __syncthreads();
  // phase 3: P2 -> LDS (overwrite M)
#pragma unroll
  for (int v = 0; v < 8; ++v)
#pragma unroll
    for (int u = 0; u < 8; ++u) sm2[(8 * tr + v) * SM + tc + 16 * u] = p2[v][u];
  __syncthreads();

  // phase 4: K = P2 @ P2 + a I   (fp64 regs, 8x8 per thread)
  double kr[8][8];
#pragma unroll
  for (int v = 0; v < 8; ++v)
#pragma unroll
    for (int u = 0; u < 8; ++u)
      kr[v][u] = ((8 * tr + v) == (tc + 16 * u)) ? a4 : 0.0;
  for (int k = 0; k < NN; ++k) {
    double av[8], bv[8];
#pragma unroll
    for (int v = 0; v < 8; ++v) av[v] = (double)sm2[(8 * tr + v) * SM + k];
#pragma unroll
    for (int u = 0; u < 8; ++u) bv[u] = (double)sm2[k * SM + tc + 16 * u];
#pragma unroll
    for (int v = 0; v < 8; ++v)
#pragma unroll
      for (int u = 0; u < 8; ++u) kr[v][u] = fma(av[v], bv[u], kr[v][u]);
  }
  __syncthreads();   // P2 tile dead; rowb/colb alias its LDS

  // phase 5: in-place Gauss-Jordan (SPD, no pivoting), 1 barrier per pivot
  for (int k = 0; k < NN; ++k) {
    double* br = rowb + (k & 1) * NN;
    double* bc = colb + (k & 1) * NN;
    if (tr == (k >> 3)) {                    // row-k owner lane set publishes row
      const int v = k & 7;
#pragma unroll
      for (int u = 0; u < 8; ++u) br[tc + 16 * u] = kr[v][u];
    }
    if (tc == (k & 15)) {                    // col-k owner lane set publishes col
      const int u = k >> 4;
#pragma unroll
      for (int v = 0; v < 8; ++v) bc[8 * tr + v] = kr[v][u];
    }
    __syncthreads();
    double dp = 1.0 / br[k];
    double rv[8];
#pragma unroll
    for (int u = 0; u < 8; ++u) rv[u] = br[tc + 16 * u];
#pragma unroll
    for (int v = 0; v < 8; ++v) {
      int i = 8 * tr + v;
      if (i == k) {
#pragma unroll
        for (int u = 0; u < 8; ++u) {
          int col = tc + 16 * u;
          kr[v][u] = (col == k) ? dp : kr[v][u] * dp;
        }
      } else {
        double fd = bc[i] * dp;
#pragma unroll
        for (int u = 0; u < 8; ++u) {
          int col = tc + 16 * u;
          kr[v][u] = (col == k) ? -fd : fma(-fd, rv[u], kr[v][u]);
        }
      }
    }
  }

  // phase 6: accumulate W
  float* Wg = W + (size_t)g * NN * NN;
#pragma unroll
  for (int v = 0; v < 8; ++v)
#pragma unroll
    for (int u = 0; u < 8; ++u)
      atomicAdd(&Wg[(8 * tr + v) * NN + tc + 16 * u], (float)(coef * kr[v][u]));
}

// ---------------------------------------------------------------------------
// K3a: Y = X - W @ X  per (graph, d-chunk of 128); also per-chunk emb (col means)
// Uses W symmetry: reads W by rows (conflict-free).
// ---------------------------------------------------------------------------
__global__ __launch_bounds__(256, 2) void k3a_y(
    const float* __restrict__ x, const float* __restrict__ rs,
    const float* __restrict__ W, float* __restrict__ Y,
    float* __restrict__ emb, int F0, int R, int DTOT, int NCH,
    float rscale) {
  extern __shared__ float sm3[];
  float* ldsW = sm3;                 // 128*129
  float* ldsX = sm3 + NN * SM;       // 128*129
  const int bid = blockIdx.x;
  const int g = bid / NCH;
  const int c = bid % NCH;
  const int d0 = c * 128;
  const int tid = threadIdx.x, tr = tid >> 4, tc = tid & 15;

  const float* Wg = W + (size_t)g * NN * NN;
  for (int e = tid; e < NN * NN; e += 256) {
    int k = e >> 7, i = e & 127;
    ldsW[k * SM + i] = Wg[e];
  }
  const float* xg = x + (size_t)g * NN * F0;
  const float* rg = rs + (size_t)g * NN * R;
  for (int e = tid; e < NN * NN; e += 256) {
    int k = e >> 7, dl = e & 127;
    int d = d0 + dl;
    float v = 0.f;
    if (d < DTOT) v = (d < F0) ? xg[k * F0 + d] : rg[k * R + (d - F0)] * rscale;
    ldsX[k * SM + dl] = v;
  }
  __syncthreads();

  float acc[8][8];
#pragma unroll
  for (int v = 0; v < 8; ++v)
#pragma unroll
    for (int u = 0; u < 8; ++u) acc[v][u] = 0.f;
  for (int k = 0; k < NN; ++k) {
    float wv[8], xv[8];
#pragma unroll
    for (int v = 0; v < 8; ++v) wv[v] = ldsW[k * SM + 8 * tr + v];  // W[k][i] == W[i][k]
#pragma unroll
    for (int u = 0; u < 8; ++u) xv[u] = ldsX[k * SM + tc + 16 * u];
#pragma unroll
    for (int v = 0; v < 8; ++v)
#pragma unroll
      for (int u = 0; u < 8; ++u) acc[v][u] = fmaf(wv[v], xv[u], acc[v][u]);
  }
  // y = x - acc ; write Y; keep y in acc for emb partials
  float* Yg = Y + (size_t)g * NN * 1152;
#pragma unroll
  for (int v = 0; v < 8; ++v)
#pragma unroll
    for (int u = 0; u < 8; ++u) {
      float yv = ldsX[(8 * tr + v) * SM + tc + 16 * u] - acc[v][u];
      acc[v][u] = yv;
      Yg[(8 * tr + v) * 1152 + d0 + tc + 16 * u] = yv;
    }
  __syncthreads();                    // ldsW dead -> reuse as emb partial buffer
  float* embp = ldsW;                 // [16][128]
#pragma unroll
  for (int u = 0; u < 8; ++u) {
    float s = 0.f;
#pragma unroll
    for (int v = 0; v < 8; ++v) s += acc[v][u];
    embp[tr * 128 + tc + 16 * u] = s;
  }
  __syncthreads();
  if (tid < 128) {
    int d = d0 + tid;
    if (d < DTOT) {
      float s = 0.f;
      for (int t = 0; t < 16; ++t) s += embp[t * 128 + tid];
      emb[(size_t)g * 1152 + d] = s * (1.f / 128.f);
    }
  }
}

// ---------------------------------------------------------------------------
// K3b: G += Ychunk @ Ychunk^T  per (graph, d-chunk), via transposed LDS tile
// ---------------------------------------------------------------------------
__global__ __launch_bounds__(256, 2) void k3b_gram(
    const float* __restrict__ Y, float* __restrict__ G,
    int DTOT, int NCH) {
  extern __shared__ float sm4[];     // Yt[128 d][132]
  const int ST = 132;
  const int bid = blockIdx.x;
  const int g = bid / NCH, c = bid % NCH, d0 = c * 128;
  const int tid = threadIdx.x, tr = tid >> 4, tc = tid & 15;
  const float* Yg = Y + (size_t)g * NN * 1152;
  for (int e = tid; e < NN * NN; e += 256) {
    int i = e >> 7, dl = e & 127;
    int d = d0 + dl;
    sm4[dl * ST + i] = (d < DTOT) ? Yg[i * 1152 + d] : 0.f;
  }
  __syncthreads();
  float gg[8][8];
#pragma unroll
  for (int v = 0; v < 8; ++v)
#pragma unroll
    for (int u = 0; u < 8; ++u) gg[v][u] = 0.f;
  for (int dl = 0; dl < 128; ++dl) {
    float av[8], bv[8];
#pragma unroll
    for (int v = 0; v < 8; ++v) av[v] = sm4[dl * ST + 8 * tr + v];
#pragma unroll
    for (int u = 0; u < 8; ++u) bv[u] = sm4[dl * ST + tc + 16 * u];
#pragma unroll
    for (int v = 0; v < 8; ++v)
#pragma unroll
      for (int u = 0; u < 8; ++u) gg[v][u] = fmaf(av[v], bv[u], gg[v][u]);
  }
  float* Gg = G + (size_t)g * NN * NN;
#pragma unroll
  for (int v = 0; v < 8; ++v)
#pragma unroll
    for (int u = 0; u < 8; ++u)
      atomicAdd(&Gg[(8 * tr + v) * NN + tc + 16 * u], gg[v][u]);
}

// ---------------------------------------------------------------------------
// K4: sp_g = -sum_ij |G_ij| / (n_i n_j) / N^2 ,  n_i = max(sqrt(G_ii), 1e-12)
// ---------------------------------------------------------------------------
__global__ __launch_bounds__(256) void k4_sp(const float* __restrict__ G,
                                             double* __restrict__ spt) {
  __shared__ float inr[NN];
  __shared__ double red[4];
  const int g = blockIdx.x, tid = threadIdx.x;
  const float* Gg = G + (size_t)g * NN * NN;
  if (tid < NN) {
    float n = sqrtf(fmaxf(Gg[tid * NN + tid], 0.f));
    inr[tid] = 1.f / fmaxf(n, 1e-12f);
  }
  __syncthreads();
  double s = 0.0;
  for (int e = tid; e < NN * NN; e += 256) {
    int i = e >> 7, j = e & 127;
    s += (double)(fabsf(Gg[e]) * inr[i] * inr[j]);
  }
  for (int off = 32; off; off >>= 1) s += __shfl_down(s, off);
  int wave = tid >> 6, lane = tid & 63;
  if (lane == 0) red[wave] = s;
  __syncthreads();
  if (tid == 0) spt[g] = -(red[0] + red[1] + red[2] + red[3]) / (double)(NN * NN);
}

// ---------------------------------------------------------------------------
// K5a: 64x64 pairwise-distance matrix over embeddings
// ---------------------------------------------------------------------------
__global__ __launch_bounds__(256) void k5a_cdist(const float* __restrict__ emb,
                                                 float* __restrict__ Dm, int DTOT) {
  __shared__ float red[4];
  const int i = blockIdx.x, tid = threadIdx.x;
  float ei[5];
#pragma unroll
  for (int s2 = 0; s2 < 5; ++s2) {
    int d = tid + 256 * s2;
    ei[s2] = (d < DTOT) ? emb[(size_t)i * 1152 + d] : 0.f;
  }
  for (int j = 0; j < 64; ++j) {
    float acc = 0.f;
#pragma unroll
    for (int s2 = 0; s2 < 5; ++s2) {
      int d = tid + 256 * s2;
      if (d < DTOT) {
        float df = ei[s2] - emb[(size_t)j * 1152 + d];
        acc = fmaf(df, df, acc);
      }
    }
    for (int off = 32; off; off >>= 1) acc += __shfl_down(acc, off);
    int wave = tid >> 6, lane = tid & 63;
    if (lane == 0) red[wave] = acc;
    __syncthreads();
    if (tid == 0) {
      float d2 = red[0] + red[1] + red[2] + red[3];
      Dm[i * 64 + j] = (d2 > 0.f) ? sqrtf(d2) : 0.f;
    }
    __syncthreads();
  }
}

// ---------------------------------------------------------------------------
// K5b: final scalar (single wave)
// ---------------------------------------------------------------------------
__global__ __launch_bounds__(64) void k5b_final(
    const float* __restrict__ Dm, const double* __restrict__ spt,
    const float* __restrict__ C, int NF,
    const int* __restrict__ ncls, float* __restrict__ out) {
  const int lane = threadIdx.x;    // 64 threads = 1 wave
  const int nc = ncls[0];
  // sparsity_fwd = sum_i sp_i * B^{-(B-i)}
  double spf = spt[lane] * exp(-((double)(64 - lane)) * log(64.0));
  for (int off = 32; off; off >>= 1) spf += __shfl_down(spf, off);

  double hl1 = 0.0, hl2 = 0.0;
  const double beta = 1.0 / (double)nc + 1e-13;
  for (int cc = 0; cc < nc; ++cc) {
    bool ip = (lane % nc) == cc;
    double ps = 0.0, ns = 0.0;
    for (int j = 0; j < 64; ++j) {
      double dv = (double)Dm[lane * 64 + j];
      bool jp = (j % nc) == cc;
      if (ip && jp) ps += dv;
      if (!ip && !jp) ns += dv;
    }
    for (int off = 32; off; off >>= 1) {
      ps += __shfl_down(ps, off);
      ns += __shfl_down(ns, off);
    }
    int npos = 0;
    for (int q = 0; q < 64; ++q) if (q % nc == cc) npos++;
    int nneg = 64 - npos;
    hl2 += ps / ((double)npos * (double)npos);
    hl1 += -(ns / ((double)nneg * (double)nneg)) / beta;
  }
  if (lane == 0) {
    double l1 = 0.0, l2 = 0.0;
    for (int q = 0; q < NF; ++q) { double cv = (double)C[q]; l1 += fabs(cv); l2 += cv * cv; }
    l2 = sqrt(l2); if (l2 < 1e-12) l2 = 1e-12;
    double dims = sqrt((double)NF);
    double sc = (dims - l1 / l2) / (dims - 1.0);
    out[0] = (float)(sc + hl2 + hl1 + spf);
  }
}

// ---------------------------------------------------------------------------
extern "C" void kernel_launch(void* const* d_in, const int* in_sizes, int n_in,
                              void* d_out, int out_size, void* d_ws, size_t ws_size,
                              hipStream_t stream) {
  (void)n_in; (void)out_size; (void)ws_size;
  const float* x    = (const float*)d_in[0];
  const float* rs   = (const float*)d_in[1];
  const float* C    = (const float*)d_in[2];
  const int*   esrc = (const int*)d_in[3];
  const int*   edst = (const int*)d_in[4];
  const int*   ncls = (const int*)d_in[5];
  float* out = (float*)d_out;

  const int F0   = in_sizes[0] / (64 * 128);
  const int R    = in_sizes[1] / (64 * 128);
  const int NF   = in_sizes[2];
  const int E    = in_sizes[3] / 64;
  const int DTOT = F0 + R;
  const int NCH  = (DTOT + 127) / 128;
  const float rscale = (float)(1.0 / sqrt((double)R));

  char* ws = (char*)d_ws;
  size_t off = 0;
  float*  L   = (float*)(ws + off);  off += (size_t)64 * NN * NN * 4;     // 4 MiB
  float*  W   = (float*)(ws + off);  off += (size_t)64 * NN * NN * 4;     // 4 MiB
  float*  Y   = (float*)(ws + off);  off += (size_t)64 * NN * 1152 * 4;   // 36 MiB
  float*  G   = (float*)(ws + off);  off += (size_t)64 * NN * NN * 4;     // 4 MiB
  float*  emb = (float*)(ws + off);  off += (size_t)64 * 1152 * 4;
  double* spt = (double*)(ws + off); off += (size_t)64 * 8;
  float*  Dm  = (float*)(ws + off);  off += (size_t)64 * 64 * 4;

  hipMemsetAsync(W, 0, (size_t)64 * NN * NN * 4, stream);
  hipMemsetAsync(G, 0, (size_t)64 * NN * NN * 4, stream);

  const int lds1  = (NN * SM + NN) * 4;     // 66560
  const int lds2  = (NN * SM) * 4;          // 66048
  const int lds3a = (NN * SM) * 4 * 2;      // 132096
  const int lds3b = NN * 132 * 4;           // 67584
  hipFuncSetAttribute((const void*)k1_laplacian, hipFuncAttributeMaxDynamicSharedMemorySize, lds1);
  hipFuncSetAttribute((const void*)k2_filter,    hipFuncAttributeMaxDynamicSharedMemorySize, lds2);
  hipFuncSetAttribute((const void*)k3a_y,        hipFuncAttributeMaxDynamicSharedMemorySize, lds3a);
  hipFuncSetAttribute((const void*)k3b_gram,     hipFuncAttributeMaxDynamicSharedMemorySize, lds3b);

  k1_laplacian<<<64, 256, lds1, stream>>>(esrc, edst, E, L);
  k2_filter<<<64 * NF, 256, lds2, stream>>>(L, C, NF, W);
  k3a_y<<<64 * NCH, 256, lds3a, stream>>>(x, rs, W, Y, emb, F0, R, DTOT, NCH, rscale);
  k3b_gram<<<64 * NCH, 256, lds3b, stream>>>(Y, G, DTOT, NCH);
  k4_sp<<<64, 256, 0, stream>>>(G, spt);
  k5a_cdist<<<64, 256, 0, stream>>>(emb, Dm, DTOT);
  k5b_final<<<1, 64, 0, stream>>>(Dm, spt, C, NF, ncls, out);
}

// Round 6
// 995.784 us; speedup vs baseline: 4.2809x; 4.2809x over previous
//
#include <hip/hip_runtime.h>
#include <math.h>

#define NN 128
#define SM 129   // padded LDS stride for 128-wide f32 tiles
#define ST 130   // padded LDS stride (doubles) for the fp64 GJ matrix
#define US 17    // stride (doubles) for the Pi panel

typedef double d4 __attribute__((ext_vector_type(4)));

// ---------------------------------------------------------------------------
// K1: build symmetric-normalized Laplacian per graph
// ---------------------------------------------------------------------------
__global__ __launch_bounds__(256) void k1_laplacian(
    const int* __restrict__ src, const int* __restrict__ dst,
    int E, float* __restrict__ Lout) {
  extern __shared__ float sm1[];            // A[128*129] + dinv[128]
  float* A    = sm1;
  float* dinv = sm1 + NN * SM;
  const int g   = blockIdx.x;
  const int tid = threadIdx.x;

  for (int e = tid; e < NN * NN; e += 256) {
    int i = e >> 7, j = e & 127;
    A[i * SM + j] = 0.f;
  }
  __syncthreads();
  const int* s = src + (size_t)g * E;
  const int* d = dst + (size_t)g * E;
  for (int e = tid; e < E; e += 256) {
    int a = s[e], b = d[e];
    A[a * SM + b] = 1.f;     // benign races: all write 1.0
    A[b * SM + a] = 1.f;
  }
  __syncthreads();
  if (tid < NN) {
    float acc = 0.f;
    for (int j = 0; j < NN; ++j) acc += A[tid * SM + j];
    dinv[tid] = (acc > 0.f) ? (float)(1.0 / sqrt((double)acc)) : 0.f;
  }
  __syncthreads();
  float* Lg = Lout + (size_t)g * NN * NN;
  for (int e = tid; e < NN * NN; e += 256) {
    int i = e >> 7, j = e & 127;
    Lg[e] = ((i == j) ? 1.f : 0.f) - dinv[i] * dinv[j] * A[i * SM + j];
  }
}

// ---------------------------------------------------------------------------
// K2 (R6): per (graph,filter) invert K = (L-bI)^4 + aI with fp64 MFMA
// (v_mfma_f64_16x16x4) + blocked Gauss-Jordan (NB=16), LAYOUT-PROOF:
//
// R5 failed with garbage (absmax 467). The D-fragment row mapping of the f64
// MFMA was assumed (4*quad+reg, the measured f32 16x16 map) but is unverified
// for f64. Fix: RUNTIME PROBE. Two MFMAs with known operands give every lane
// its exact (row, col) index per output register:
//   probe1: A[i][k]=i (a=lane&15), B=1   -> D[i][j] = 4*i  -> row indices
//   probe2: A=1, B[k][j]=j (b=lane&15)   -> D[i][j] = 4*j  -> col indices
// A/B operand layouts are forced by cardinality (lane&15 must index the
// size-16 dim; lane>>4 the size-4 K dim). All D stores / C preloads use the
// probed indices -> correct under ANY bijective D mapping.
//
// Also: U panel eliminated (stored in place into cols K; each wave owns its
// own 16-row band so the overwrite is wave-local, dataflow-ordered). LDS
// 152.7 KB -> 135.3 KB (k3a's 132 KB is proven launchable).
//
// LDS map: [0,66048) f32 M/P2 (128x129); [0,133120) f64 A 128x130 (aliases
// f32 region after a barrier); [133120,135296) f64 Pi 16x17.
//
// Blocked GJ step t (K = rows/cols 16t..16t+15), == scalar GJ at NB=1:
//   Pi = inv(A[K][K])                        (wave 0, shuffles, SPD no-pivot)
//   A[:,K] := -(A[:,K]_old @ Pi); A[K][K] := Pi   (per-wave in place)
//   A[r][c] += A[r][K]_new @ A[K][c]_old   r,c not in K  (MFMA trailing)
//   A[K][c] := Pi @ A[K][c]_old            c not in K    (row panel)
// ---------------------------------------------------------------------------
__global__ __launch_bounds__(512, 2) void k2_filter(
    const float* __restrict__ L, const float* __restrict__ C,
    int NF, float* __restrict__ W) {
  extern __shared__ char smraw[];
  float*  smf = (float*)smraw;                       // M / P2
  double* A   = (double*)smraw;                      // fp64 GJ matrix
  double* Piv = (double*)(smraw + 133120);

  const int bid = blockIdx.x;
  const int g = bid / NF, f = bid % NF;
  const int tid = threadIdx.x;
  const int wv = tid >> 6, ln = tid & 63;
  const int m  = ln & 15, kq = ln >> 4;   // forced A/B operand coords

  double csum = 0.0;
  for (int q = 0; q < NF; ++q) { double c = (double)C[q]; csum += c * c; }
  double cn = sqrt(csum); if (cn < 1e-12) cn = 1e-12;
  const double a4 = 6.25e-6;                         // (STEP/2)^4
  const double coef = 1.4142135623730951 * a4 * ((double)C[f] / cn);
  const float  bf = (float)((double)f * 0.1);

  // --- runtime D-layout probe (2 MFMAs; layout-proof) ---
  int rIdx[4], cIdx[4];
  {
    d4 z = {0.0, 0.0, 0.0, 0.0};
    d4 pr = __builtin_amdgcn_mfma_f64_16x16x4f64((double)m, 1.0, z, 0, 0, 0);
    d4 pc = __builtin_amdgcn_mfma_f64_16x16x4f64(1.0, (double)m, z, 0, 0, 0);
#pragma unroll
    for (int r = 0; r < 4; ++r) {
      rIdx[r] = ((int)(pr[r] * 0.25 + 0.5)) & 15;
      cIdx[r] = ((int)(pc[r] * 0.25 + 0.5)) & 15;
    }
  }

  // phase 1: M = L - b I  (f32 LDS)
  const float* Lg = L + (size_t)g * NN * NN;
  for (int e = tid; e < NN * NN; e += 512) {
    int i = e >> 7, j = e & 127;
    float v = Lg[e];
    if (i == j) v -= bf;
    smf[i * SM + j] = v;
  }
  __syncthreads();

  // phase 2: P2 = M @ M  (fp32, 4x8 regs/thread; numerics proven in R2-R4)
  {
    const int tr = tid >> 4;                // 0..31
    const int tc = tid & 15;
    float p2r[4][8];
#pragma unroll
    for (int v = 0; v < 4; ++v)
#pragma unroll
      for (int u = 0; u < 8; ++u) p2r[v][u] = 0.f;
    for (int k = 0; k < NN; ++k) {
      float av[4], bv[8];
#pragma unroll
      for (int v = 0; v < 4; ++v) av[v] = smf[(4 * tr + v) * SM + k];
#pragma unroll
      for (int u = 0; u < 8; ++u) bv[u] = smf[k * SM + tc + 16 * u];
#pragma unroll
      for (int v = 0; v < 4; ++v)
#pragma unroll
        for (int u = 0; u < 8; ++u) p2r[v][u] = fmaf(av[v], bv[u], p2r[v][u]);
    }
    __syncthreads();
#pragma unroll
    for (int v = 0; v < 4; ++v)
#pragma unroll
      for (int u = 0; u < 8; ++u) smf[(4 * tr + v) * SM + tc + 16 * u] = p2r[v][u];
    __syncthreads();
  }

  // phase 3: P4 = P2 @ P2 + a I  via fp64 MFMA; wave w owns row-band 16w.
  {
    d4 acc[8];
#pragma unroll
    for (int cb = 0; cb < 8; ++cb)
#pragma unroll
      for (int r = 0; r < 4; ++r)
        acc[cb][r] = ((16 * wv + rIdx[r]) == (16 * cb + cIdx[r])) ? a4 : 0.0;
    for (int kc = 0; kc < 32; ++kc) {
      double a = (double)smf[(16 * wv + m) * SM + 4 * kc + kq];
#pragma unroll
      for (int cb = 0; cb < 8; ++cb) {
        double b = (double)smf[(4 * kc + kq) * SM + 16 * cb + m];
        acc[cb] = __builtin_amdgcn_mfma_f64_16x16x4f64(a, b, acc[cb], 0, 0, 0);
      }
    }
    __syncthreads();   // all P2 reads done; f32 region dead -> write A
#pragma unroll
    for (int cb = 0; cb < 8; ++cb)
#pragma unroll
      for (int r = 0; r < 4; ++r)
        A[(16 * wv + rIdx[r]) * ST + 16 * cb + cIdx[r]] = acc[cb][r];
    __syncthreads();
  }

  // phase 4: blocked Gauss-Jordan inversion, 8 steps of NB=16
  for (int t = 0; t < 8; ++t) {
    const int K0 = 16 * t;

    // (b) wave 0: Pi = inv(A[K][K]) via 16 shuffle-pivots (layout-free)
    if (wv == 0) {
      double sr[4];
#pragma unroll
      for (int r = 0; r < 4; ++r) sr[r] = A[(K0 + 4 * kq + r) * ST + K0 + m];
#pragma unroll
      for (int k = 0; k < 16; ++k) {
        const int g2 = k >> 2, rr = k & 3;
        double pv   = __shfl(sr[rr], 16 * g2 + k);
        double rowv = __shfl(sr[rr], 16 * g2 + m);
        double cv[4];
#pragma unroll
        for (int r = 0; r < 4; ++r) cv[r] = __shfl(sr[r], 16 * kq + k);
        double dp = 1.0 / pv;
#pragma unroll
        for (int r = 0; r < 4; ++r) {
          int i = 4 * kq + r;
          double nv;
          if (i == k)      nv = (m == k) ? dp : rowv * dp;
          else if (m == k) nv = -cv[r] * dp;
          else             nv = fma(-(cv[r] * dp), rowv, sr[r]);
          sr[r] = nv;
        }
      }
#pragma unroll
      for (int r = 0; r < 4; ++r) Piv[(4 * kq + r) * US + m] = sr[r];
    }
    __syncthreads();

    // (c) cols K in place: wave w band: A[band,K] := -(A[band,K]_old @ Pi);
    //     wave t writes Pi instead. Wave-local (own 16-row band), dataflow-
    //     ordered (stores depend on MFMA result of all reads) -> no barrier
    //     needed between read and overwrite.
    {
      d4 ua = {0.0, 0.0, 0.0, 0.0};
#pragma unroll
      for (int kc = 0; kc < 4; ++kc) {
        double a = A[(16 * wv + m) * ST + K0 + 4 * kc + kq];
        double b = Piv[(4 * kc + kq) * US + m];
        ua = __builtin_amdgcn_mfma_f64_16x16x4f64(a, b, ua, 0, 0, 0);
      }
#pragma unroll
      for (int r = 0; r < 4; ++r) {
        double val = (wv == t) ? Piv[rIdx[r] * US + cIdx[r]] : -ua[r];
        A[(16 * wv + rIdx[r]) * ST + K0 + cIdx[r]] = val;
      }
    }
    __syncthreads();

    // (d) trailing update: 49 tiles (rb!=t, cb!=t), rank-16 MFMA.
    //     Reads: cols K (the new -F*Pi), rows K at cols !=K (old), own C tile.
    //     Writes: own C tile (cols/rows not in K) -> all disjoint.
    for (int ti = wv; ti < 49; ti += 8) {
      int rbi = ti / 7, cbi = ti % 7;
      int rb = rbi + (rbi >= t), cb = cbi + (cbi >= t);
      d4 acc2;
#pragma unroll
      for (int r = 0; r < 4; ++r)
        acc2[r] = A[(16 * rb + rIdx[r]) * ST + 16 * cb + cIdx[r]];
#pragma unroll
      for (int kc = 0; kc < 4; ++kc) {
        double a = A[(16 * rb + m) * ST + K0 + 4 * kc + kq];   // U = -F*Pi
        double b = A[(K0 + 4 * kc + kq) * ST + 16 * cb + m];   // old pivot rows
        acc2 = __builtin_amdgcn_mfma_f64_16x16x4f64(a, b, acc2, 0, 0, 0);
      }
#pragma unroll
      for (int r = 0; r < 4; ++r)
        A[(16 * rb + rIdx[r]) * ST + 16 * cb + cIdx[r]] = acc2[r];
    }
    __syncthreads();

    // (f) row panel: A[K][cb] := Pi @ A[K][cb]_old, cb != t (wave-exclusive,
    //     in-place, dataflow-ordered within the wave)
    if (wv < 7) {
      int cb = wv + (wv >= t);
      d4 acc3 = {0.0, 0.0, 0.0, 0.0};
#pragma unroll
      for (int kc = 0; kc < 4; ++kc) {
        double a = Piv[m * US + 4 * kc + kq];
        double b = A[(K0 + 4 * kc + kq) * ST + 16 * cb + m];
        acc3 = __builtin_amdgcn_mfma_f64_16x16x4f64(a, b, acc3, 0, 0, 0);
      }
#pragma unroll
      for (int r = 0; r < 4; ++r)
        A[(K0 + rIdx[r]) * ST + 16 * cb + cIdx[r]] = acc3[r];
    }
    __syncthreads();
  }

  // phase 5: W += coef * K^{-1}
  float* Wg = W + (size_t)g * NN * NN;
  for (int e = tid; e < NN * NN; e += 512) {
    int i = e >> 7, j = e & 127;
    atomicAdd(&Wg[e], (float)(coef * A[i * ST + j]));
  }
}

// ---------------------------------------------------------------------------
// K3a: Y = X - W @ X  per (graph, d-chunk of 128); also per-chunk emb (col means)
// ---------------------------------------------------------------------------
__global__ __launch_bounds__(256, 2) void k3a_y(
    const float* __restrict__ x, const float* __restrict__ rs,
    const float* __restrict__ W, float* __restrict__ Y,
    float* __restrict__ emb, int F0, int R, int DTOT, int NCH,
    float rscale) {
  extern __shared__ float sm3[];
  float* ldsW = sm3;                 // 128*129
  float* ldsX = sm3 + NN * SM;       // 128*129
  const int bid = blockIdx.x;
  const int g = bid / NCH;
  const int c = bid % NCH;
  const int d0 = c * 128;
  const int tid = threadIdx.x, tr = tid >> 4, tc = tid & 15;

  const float* Wg = W + (size_t)g * NN * NN;
  for (int e = tid; e < NN * NN; e += 256) {
    int k = e >> 7, i = e & 127;
    ldsW[k * SM + i] = Wg[e];
  }
  const float* xg = x + (size_t)g * NN * F0;
  const float* rg = rs + (size_t)g * NN * R;
  for (int e = tid; e < NN * NN; e += 256) {
    int k = e >> 7, dl = e & 127;
    int d = d0 + dl;
    float v = 0.f;
    if (d < DTOT) v = (d < F0) ? xg[k * F0 + d] : rg[k * R + (d - F0)] * rscale;
    ldsX[k * SM + dl] = v;
  }
  __syncthreads();

  float acc[8][8];
#pragma unroll
  for (int v = 0; v < 8; ++v)
#pragma unroll
    for (int u = 0; u < 8; ++u) acc[v][u] = 0.f;
  for (int k = 0; k < NN; ++k) {
    float wvv[8], xv[8];
#pragma unroll
    for (int v = 0; v < 8; ++v) wvv[v] = ldsW[k * SM + 8 * tr + v];  // W symmetric
#pragma unroll
    for (int u = 0; u < 8; ++u) xv[u] = ldsX[k * SM + tc + 16 * u];
#pragma unroll
    for (int v = 0; v < 8; ++v)
#pragma unroll
      for (int u = 0; u < 8; ++u) acc[v][u] = fmaf(wvv[v], xv[u], acc[v][u]);
  }
  float* Yg = Y + (size_t)g * NN * 1152;
#pragma unroll
  for (int v = 0; v < 8; ++v)
#pragma unroll
    for (int u = 0; u < 8; ++u) {
      float yv = ldsX[(8 * tr + v) * SM + tc + 16 * u] - acc[v][u];
      acc[v][u] = yv;
      Yg[(8 * tr + v) * 1152 + d0 + tc + 16 * u] = yv;
    }
  __syncthreads();
  float* embp = ldsW;
#pragma unroll
  for (int u = 0; u < 8; ++u) {
    float s = 0.f;
#pragma unroll
    for (int v = 0; v < 8; ++v) s += acc[v][u];
    embp[tr * 128 + tc + 16 * u] = s;
  }
  __syncthreads();
  if (tid < 128) {
    int d = d0 + tid;
    if (d < DTOT) {
      float s = 0.f;
      for (int tt = 0; tt < 16; ++tt) s += embp[tt * 128 + tid];
      emb[(size_t)g * 1152 + d] = s * (1.f / 128.f);
    }
  }
}

// ---------------------------------------------------------------------------
// K3b: G += Ychunk @ Ychunk^T  per (graph, d-chunk), via transposed LDS tile
// ---------------------------------------------------------------------------
__global__ __launch_bounds__(256, 2) void k3b_gram(
    const float* __restrict__ Y, float* __restrict__ G,
    int DTOT, int NCH) {
  extern __shared__ float sm4[];     // Yt[128 d][132]
  const int STT = 132;
  const int bid = blockIdx.x;
  const int g = bid / NCH, c = bid % NCH, d0 = c * 128;
  const int tid = threadIdx.x, tr = tid >> 4, tc = tid & 15;
  const float* Yg = Y + (size_t)g * NN * 1152;
  for (int e = tid; e < NN * NN; e += 256) {
    int i = e >> 7, dl = e & 127;
    int d = d0 + dl;
    sm4[dl * STT + i] = (d < DTOT) ? Yg[i * 1152 + d] : 0.f;
  }
  __syncthreads();
  float gg[8][8];
#pragma unroll
  for (int v = 0; v < 8; ++v)
#pragma unroll
    for (int u = 0; u < 8; ++u) gg[v][u] = 0.f;
  for (int dl = 0; dl < 128; ++dl) {
    float av[8], bv[8];
#pragma unroll
    for (int v = 0; v < 8; ++v) av[v] = sm4[dl * STT + 8 * tr + v];
#pragma unroll
    for (int u = 0; u < 8; ++u) bv[u] = sm4[dl * STT + tc + 16 * u];
#pragma unroll
    for (int v = 0; v < 8; ++v)
#pragma unroll
      for (int u = 0; u < 8; ++u) gg[v][u] = fmaf(av[v], bv[u], gg[v][u]);
  }
  float* Gg = G + (size_t)g * NN * NN;
#pragma unroll
  for (int v = 0; v < 8; ++v)
#pragma unroll
    for (int u = 0; u < 8; ++u)
      atomicAdd(&Gg[(8 * tr + v) * NN + tc + 16 * u], gg[v][u]);
}

// ---------------------------------------------------------------------------
// K4: sp_g = -sum_ij |G_ij| / (n_i n_j) / N^2
// ---------------------------------------------------------------------------
__global__ __launch_bounds__(256) void k4_sp(const float* __restrict__ G,
                                             double* __restrict__ spt) {
  __shared__ float inr[NN];
  __shared__ double red[4];
  const int g = blockIdx.x, tid = threadIdx.x;
  const float* Gg = G + (size_t)g * NN * NN;
  if (tid < NN) {
    float n = sqrtf(fmaxf(Gg[tid * NN + tid], 0.f));
    inr[tid] = 1.f / fmaxf(n, 1e-12f);
  }
  __syncthreads();
  double s = 0.0;
  for (int e = tid; e < NN * NN; e += 256) {
    int i = e >> 7, j = e & 127;
    s += (double)(fabsf(Gg[e]) * inr[i] * inr[j]);
  }
  for (int off = 32; off; off >>= 1) s += __shfl_down(s, off);
  int wave = tid >> 6, lane = tid & 63;
  if (lane == 0) red[wave] = s;
  __syncthreads();
  if (tid == 0) spt[g] = -(red[0] + red[1] + red[2] + red[3]) / (double)(NN * NN);
}

// ---------------------------------------------------------------------------
// K5a: 64x64 pairwise-distance matrix over embeddings
// ---------------------------------------------------------------------------
__global__ __launch_bounds__(256) void k5a_cdist(const float* __restrict__ emb,
                                                 float* __restrict__ Dm, int DTOT) {
  __shared__ float red[4];
  const int i = blockIdx.x, tid = threadIdx.x;
  float ei[5];
#pragma unroll
  for (int s2 = 0; s2 < 5; ++s2) {
    int d = tid + 256 * s2;
    ei[s2] = (d < DTOT) ? emb[(size_t)i * 1152 + d] : 0.f;
  }
  for (int j = 0; j < 64; ++j) {
    float acc = 0.f;
#pragma unroll
    for (int s2 = 0; s2 < 5; ++s2) {
      int d = tid + 256 * s2;
      if (d < DTOT) {
        float df = ei[s2] - emb[(size_t)j * 1152 + d];
        acc = fmaf(df, df, acc);
      }
    }
    for (int off = 32; off; off >>= 1) acc += __shfl_down(acc, off);
    int wave = tid >> 6, lane = tid & 63;
    if (lane == 0) red[wave] = acc;
    __syncthreads();
    if (tid == 0) {
      float d2 = red[0] + red[1] + red[2] + red[3];
      Dm[i * 64 + j] = (d2 > 0.f) ? sqrtf(d2) : 0.f;
    }
    __syncthreads();
  }
}

// ---------------------------------------------------------------------------
// K5b: final scalar (single wave)
// ---------------------------------------------------------------------------
__global__ __launch_bounds__(64) void k5b_final(
    const float* __restrict__ Dm, const double* __restrict__ spt,
    const float* __restrict__ C, int NF,
    const int* __restrict__ ncls, float* __restrict__ out) {
  const int lane = threadIdx.x;
  const int nc = ncls[0];
  double spf = spt[lane] * exp(-((double)(64 - lane)) * log(64.0));
  for (int off = 32; off; off >>= 1) spf += __shfl_down(spf, off);

  double hl1 = 0.0, hl2 = 0.0;
  const double beta = 1.0 / (double)nc + 1e-13;
  for (int cc = 0; cc < nc; ++cc) {
    bool ip = (lane % nc) == cc;
    double ps = 0.0, ns = 0.0;
    for (int j = 0; j < 64; ++j) {
      double dv = (double)Dm[lane * 64 + j];
      bool jp = (j % nc) == cc;
      if (ip && jp) ps += dv;
      if (!ip && !jp) ns += dv;
    }
    for (int off = 32; off; off >>= 1) {
      ps += __shfl_down(ps, off);
      ns += __shfl_down(ns, off);
    }
    int npos = 0;
    for (int q = 0; q < 64; ++q) if (q % nc == cc) npos++;
    int nneg = 64 - npos;
    hl2 += ps / ((double)npos * (double)npos);
    hl1 += -(ns / ((double)nneg * (double)nneg)) / beta;
  }
  if (lane == 0) {
    double l1 = 0.0, l2 = 0.0;
    for (int q = 0; q < NF; ++q) { double cv = (double)C[q]; l1 += fabs(cv); l2 += cv * cv; }
    l2 = sqrt(l2); if (l2 < 1e-12) l2 = 1e-12;
    double dims = sqrt((double)NF);
    double sc = (dims - l1 / l2) / (dims - 1.0);
    out[0] = (float)(sc + hl2 + hl1 + spf);
  }
}

// ---------------------------------------------------------------------------
extern "C" void kernel_launch(void* const* d_in, const int* in_sizes, int n_in,
                              void* d_out, int out_size, void* d_ws, size_t ws_size,
                              hipStream_t stream) {
  (void)n_in; (void)out_size; (void)ws_size;
  const float* x    = (const float*)d_in[0];
  const float* rs   = (const float*)d_in[1];
  const float* C    = (const float*)d_in[2];
  const int*   esrc = (const int*)d_in[3];
  const int*   edst = (const int*)d_in[4];
  const int*   ncls = (const int*)d_in[5];
  float* out = (float*)d_out;

  const int F0   = in_sizes[0] / (64 * 128);
  const int R    = in_sizes[1] / (64 * 128);
  const int NF   = in_sizes[2];
  const int E    = in_sizes[3] / 64;
  const int DTOT = F0 + R;
  const int NCH  = (DTOT + 127) / 128;
  const float rscale = (float)(1.0 / sqrt((double)R));

  char* ws = (char*)d_ws;
  size_t off = 0;
  float*  L   = (float*)(ws + off);  off += (size_t)64 * NN * NN * 4;
  float*  W   = (float*)(ws + off);  off += (size_t)64 * NN * NN * 4;
  float*  Y   = (float*)(ws + off);  off += (size_t)64 * NN * 1152 * 4;
  float*  G   = (float*)(ws + off);  off += (size_t)64 * NN * NN * 4;
  float*  emb = (float*)(ws + off);  off += (size_t)64 * 1152 * 4;
  double* spt = (double*)(ws + off); off += (size_t)64 * 8;
  float*  Dm  = (float*)(ws + off);  off += (size_t)64 * 64 * 4;

  hipMemsetAsync(W, 0, (size_t)64 * NN * NN * 4, stream);
  hipMemsetAsync(G, 0, (size_t)64 * NN * NN * 4, stream);

  const int lds1  = (NN * SM + NN) * 4;       // 66560
  const int lds2  = 135296;                   // A(133120) + Pi(2176)
  const int lds3a = (NN * SM) * 4 * 2;        // 132096
  const int lds3b = NN * 132 * 4;             // 67584
  hipFuncSetAttribute((const void*)k1_laplacian, hipFuncAttributeMaxDynamicSharedMemorySize, lds1);
  hipFuncSetAttribute((const void*)k2_filter,    hipFuncAttributeMaxDynamicSharedMemorySize, lds2);
  hipFuncSetAttribute((const void*)k3a_y,        hipFuncAttributeMaxDynamicSharedMemorySize, lds3a);
  hipFuncSetAttribute((const void*)k3b_gram,     hipFuncAttributeMaxDynamicSharedMemorySize, lds3b);

  k1_laplacian<<<64, 256, lds1, stream>>>(esrc, edst, E, L);
  k2_filter<<<64 * NF, 512, lds2, stream>>>(L, C, NF, W);
  k3a_y<<<64 * NCH, 256, lds3a, stream>>>(x, rs, W, Y, emb, F0, R, DTOT, NCH, rscale);
  k3b_gram<<<64 * NCH, 256, lds3b, stream>>>(Y, G, DTOT, NCH);
  k4_sp<<<64, 256, 0, stream>>>(G, spt);
  k5a_cdist<<<64, 256, 0, stream>>>(emb, Dm, DTOT);
  k5b_final<<<1, 64, 0, stream>>>(Dm, spt, C, NF, ncls, out);
}